// Round 6
// baseline (703.443 us; speedup 1.0000x reference)
//
#include <hip/hip_runtime.h>
#include <math.h>

typedef unsigned short u16;

#define BSZ 128
#define SEQL 128
#define DIM 768
#define FEAT 1024
#define WORDS_OUT_ELEMS (BSZ * FEAT * 126)  // 16,515,072

typedef __attribute__((ext_vector_type(8))) __bf16 bf16x8;
typedef __attribute__((ext_vector_type(4))) float f32x4;

__device__ __forceinline__ u16 f2bf(float x) {
  unsigned u = __float_as_uint(x);
  u += 0x7FFFu + ((u >> 16) & 1u);
  return (u16)(u >> 16);
}

__device__ __forceinline__ void gld_lds16(const void* g, void* l) {
  __builtin_amdgcn_global_load_lds(
      (const __attribute__((address_space(1))) void*)g,
      (__attribute__((address_space(3))) void*)l, 16, 0, 0);
}

#define WAITVM0 asm volatile("s_waitcnt vmcnt(0)" ::: "memory")

// ---------------- fused fp32 -> bf16 convert ----------------
#define N4_WORDS 3145728
#define N4_W2 393216
#define N4_W3 589824
#define N4_W4 786432
#define N4_TOTAL (N4_WORDS + N4_W2 + N4_W3 + N4_W4)  // 4,915,200

__global__ __launch_bounds__(256) void cvt_all(const float* __restrict__ words,
                                               const float* __restrict__ W2,
                                               const float* __restrict__ W3,
                                               const float* __restrict__ W4,
                                               u16* __restrict__ dA, u16* __restrict__ d2,
                                               u16* __restrict__ d3, u16* __restrict__ d4) {
  int i = blockIdx.x * 256 + threadIdx.x;
  if (i >= N4_TOTAL) return;
  const float* src;
  u16* dst;
  int j = i;
  if (j < N4_WORDS) {
    src = words; dst = dA;
  } else if ((j -= N4_WORDS) < N4_W2) {
    src = W2; dst = d2;
  } else if ((j -= N4_W2) < N4_W3) {
    src = W3; dst = d3;
  } else {
    j -= N4_W3; src = W4; dst = d4;
  }
  float4 v = ((const float4*)src)[j];
  ushort4 o;
  o.x = f2bf(v.x); o.y = f2bf(v.y); o.z = f2bf(v.z); o.w = f2bf(v.w);
  ((ushort4*)dst)[j] = o;
}

// ---------------- conv GEMM ----------------
// R8: barrier-free k-loop + W-direct-from-global.
// R7 post-mortem: phase barriers exposed ds_read latency inside each region
// (reads AFTER leading barrier) -> serial again (232us, 43.7%). Model: MFMA
// 110us + LDS 102us serial in ALL barrier-per-k-step structures (R5 212,
// R7 232 ~ sum). Fix: (1) W frags loaded global->reg (dwordx4, 16B/lane,
// same layout staging used), prefetched 1 k-step ahead -- register pipeline,
// no barriers, shifts 8 of 24 LDS reads/wave/step to the parallel VMEM/L2
// pipe (per-XCD W set 1.77MB < 4MB L2; linear-id XCD round-robin pins
// tile_n/XCD). LDS floor 102->68us << MFMA 110us. (2) barriers only at d0
// boundaries (X dbuf swap): waves free-run ~K*64 MFMA between barriers,
// cross-wave read/MFMA overlap + compiler kc-pipelining (no sched_barrier).
// LDS 132KB (X dbuf 2x64K + 4K guard for k-shift OOB reads), 1 blk/CU,
// 8 waves. VGPR ~245 (acc 128 + wf/wfn 64 + af 32 + addr) < 256 ceiling.
__device__ __forceinline__ void stage_tile512(const u16* __restrict__ gbase, int stride,
                                              u16* __restrict__ ldsbase, int wave, int lane) {
  // 128 rows x 64 cols (16 KB): 2 passes x 512 threads x 16 B
#pragma unroll
  for (int p = 0; p < 2; ++p) {
    int slot = p * 512 + wave * 64 + lane;
    int r = slot >> 3, c = slot & 7;
    const u16* src = gbase + (size_t)r * stride + ((c ^ (r & 7)) * 8);
    unsigned uofs = __builtin_amdgcn_readfirstlane((unsigned)((p * 512 + wave * 64) * 8));
    gld_lds16(src, ldsbase + uofs);
  }
}

template <int K>
__device__ __forceinline__ void run_branch(const u16* __restrict__ A,
                                           const u16* __restrict__ W,
                                           const float* __restrict__ bias,
                                           u16* __restrict__ C,
                                           int b0, int tile_n, u16* lds) {
  const int KD = K * 768;
  const int Lp = 129 - K;  // 127,126,125
  const int tid = threadIdx.x;
  const int wave = tid >> 6, lane = tid & 63;
  const int frow = lane & 15;
  const int fq = lane >> 4;
  const int wq = wave >> 1;        // batch of the quad (0..3)
  const int wn = (wave & 1) * 64;  // N-half

  const u16* xg = A + (size_t)b0 * 98304;  // batch q at +q*98304
  const u16* wg = W + (size_t)tile_n * 128 * KD;
  // per-lane W fragment base pointers (row = wn+ni*16+frow, chunk base fq*8)
  const u16* pW[4];
#pragma unroll
  for (int ni = 0; ni < 4; ++ni)
    pW[ni] = wg + (size_t)(wn + ni * 16 + frow) * KD + fq * 8;

  f32x4 acc[8][4];
#pragma unroll
  for (int mi = 0; mi < 8; ++mi)
#pragma unroll
    for (int ni = 0; ni < 4; ++ni) acc[mi][ni] = 0.0f;

  // prologue: stage X(d0=0), preload W frags for s=0
#pragma unroll
  for (int q = 0; q < 4; ++q)
    stage_tile512(xg + (size_t)q * 98304, 768, lds + q * 8192, wave, lane);
  bf16x8 wf[8];  // [kc*4+ni], current step
#pragma unroll
  for (int kc = 0; kc < 2; ++kc)
#pragma unroll
    for (int ni = 0; ni < 4; ++ni)
      wf[kc * 4 + ni] = *(const bf16x8*)(pW[ni] + kc * 32);
  WAITVM0;
  __builtin_amdgcn_sched_barrier(0);
  __syncthreads();

  for (int d0i = 0; d0i < 12; ++d0i) {
    const int dd = d0i * 64;
    u16* Xcur = (d0i & 1) ? (lds + 32768) : lds;
    u16* Xnxt = (d0i & 1) ? lds : (lds + 32768);
    const u16* xb = Xcur + wq * 8192;
    // stage next X quad once per d0; has the whole region (~K*64 MFMA) to land
    if (d0i < 11) {
#pragma unroll
      for (int q = 0; q < 4; ++q)
        stage_tile512(xg + (size_t)q * 98304 + dd + 64, 768, Xnxt + q * 8192, wave, lane);
    }
#pragma unroll
    for (int k = 0; k < K; ++k) {
      // prefetch W frags for step s+1 (register pipeline, no barriers)
      bf16x8 wfn[8];
      const bool havenext = (k + 1 < K) || (d0i < 11);
      if (havenext) {
        const int noff = (k + 1 < K) ? ((k + 1) * 768 + dd) : dd + 64;  // nk*768+nd
#pragma unroll
        for (int kc = 0; kc < 2; ++kc)
#pragma unroll
          for (int ni = 0; ni < 4; ++ni)
            wfn[kc * 4 + ni] = *(const bf16x8*)(pW[ni] + noff + kc * 32);
      }
#pragma unroll
      for (int kc = 0; kc < 2; ++kc) {
        bf16x8 af[8];
#pragma unroll
        for (int mi = 0; mi < 8; ++mi) {
          int row = mi * 16 + frow + k;  // k-shifted raw-row read
          af[mi] = *(const bf16x8*)&xb[(row * 8 + ((kc * 4 + fq) ^ (row & 7))) * 8];
        }
        __builtin_amdgcn_s_setprio(1);
#pragma unroll
        for (int mi = 0; mi < 8; ++mi)
#pragma unroll
          for (int ni = 0; ni < 4; ++ni)
            acc[mi][ni] = __builtin_amdgcn_mfma_f32_16x16x32_bf16(af[mi], wf[kc * 4 + ni],
                                                                  acc[mi][ni], 0, 0, 0);
        __builtin_amdgcn_s_setprio(0);
      }
      if (havenext) {
#pragma unroll
        for (int j = 0; j < 8; ++j) wf[j] = wfn[j];
      }
    }
    __syncthreads();  // X dbuf swap (compiler drains vmcnt/lgkmcnt here)
  }

  float bv[4];
#pragma unroll
  for (int ni = 0; ni < 4; ++ni) bv[ni] = bias[tile_n * 128 + wn + ni * 16 + frow];
  const int bb = b0 + wq;
#pragma unroll
  for (int mi = 0; mi < 8; ++mi) {
#pragma unroll
    for (int r = 0; r < 4; ++r) {
      int mg = mi * 16 + fq * 4 + r;  // row within this wave's batch
      if (mg < Lp) {
        ushort4 hs;
        hs.x = f2bf(fmaxf(acc[mi][0][r] + bv[0], 0.0f));
        hs.y = f2bf(fmaxf(acc[mi][1][r] + bv[1], 0.0f));
        hs.z = f2bf(fmaxf(acc[mi][2][r] + bv[2], 0.0f));
        hs.w = f2bf(fmaxf(acc[mi][3][r] + bv[3], 0.0f));
        *(ushort4*)(C + (size_t)(bb * Lp + mg) * FEAT + tile_n * 128 + wn + frow * 4) = hs;
      }
    }
  }
}

__global__ __launch_bounds__(512, 1) void gemm_fused(const u16* __restrict__ A,
                                                     const u16* __restrict__ W2,
                                                     const u16* __restrict__ W3,
                                                     const u16* __restrict__ W4,
                                                     const float* __restrict__ b2,
                                                     const float* __restrict__ b3,
                                                     const float* __restrict__ b4,
                                                     u16* __restrict__ Ca,
                                                     u16* __restrict__ Cb,
                                                     u16* __restrict__ Cc) {
  __shared__ u16 lds[67584];  // 132 KB: X dbuf 2x64K + 4K guard (k-shift OOB reads)
  const int tile_n = blockIdx.x;
  const int z = blockIdx.y;
  const int b0 = blockIdx.z * 4;
  if (z == 0)
    run_branch<2>(A, W2, b2, Ca, b0, tile_n, lds);
  else if (z == 1)
    run_branch<3>(A, W3, b3, Cb, b0, tile_n, lds);
  else
    run_branch<4>(A, W4, b4, Cc, b0, tile_n, lds);
}

__device__ __forceinline__ float4 load_bf4(const u16* p) {
  uint2 q = *(const uint2*)p;
  float4 r;
  r.x = __uint_as_float((q.x & 0xFFFFu) << 16);
  r.y = __uint_as_float(q.x & 0xFFFF0000u);
  r.z = __uint_as_float((q.y & 0xFFFFu) << 16);
  r.w = __uint_as_float(q.y & 0xFFFF0000u);
  return r;
}

// ---------------- combine (max over branches) + L2 norm over FEAT + transposed write ----------------
// a: (BSZ,127,FEAT) b: (BSZ,126,FEAT) c: (BSZ,125,FEAT), bf16, PERMUTED col layout
// (stored index s within a 64-col chunk holds actual col (s&3)*16 + (s>>2)).
#define CSTR 1028

__global__ __launch_bounds__(256) void combine_norm(const u16* __restrict__ a,
                                                    const u16* __restrict__ b,
                                                    const u16* __restrict__ c,
                                                    float* __restrict__ out) {
  __shared__ float comb[16 * CSTR];  // 65.8 KB
  __shared__ float red[16 * 4];
  __shared__ float inv[16];
  const int tid = threadIdx.x;
  const int wave = tid >> 6, lane = tid & 63;
  const int l0 = blockIdx.x * 16;
  const int bb = blockIdx.y;
  const int rem = (126 - l0 < 16) ? (126 - l0) : 16;  // 16, last block 14
  const int f0 = tid * 4;                       // stored (permuted) index
  const int chunk = tid >> 4, frow = tid & 15;  // de-permute params
  const int fbase = chunk * 64 + frow;          // actual col for ni=0 (then +16 per ni)

  float part[16];
#pragma unroll
  for (int l = 0; l < 16; ++l) {
    int lg = l0 + l;
    float4 v = make_float4(0.f, 0.f, 0.f, 0.f);
    if (lg < 126) {
      v = load_bf4(a + (size_t)(bb * 127 + lg) * 1024 + f0);
      if (lg < 125) {
        float4 vb = load_bf4(b + (size_t)(bb * 126 + lg) * 1024 + f0);
        v.x = fmaxf(v.x, vb.x); v.y = fmaxf(v.y, vb.y);
        v.z = fmaxf(v.z, vb.z); v.w = fmaxf(v.w, vb.w);
      }
      if (lg < 124) {
        float4 vc = load_bf4(c + (size_t)(bb * 125 + lg) * 1024 + f0);
        v.x = fmaxf(v.x, vc.x); v.y = fmaxf(v.y, vc.y);
        v.z = fmaxf(v.z, vc.z); v.w = fmaxf(v.w, vc.w);
      }
    }
    comb[l * CSTR + fbase + 0] = v.x;
    comb[l * CSTR + fbase + 16] = v.y;
    comb[l * CSTR + fbase + 32] = v.z;
    comb[l * CSTR + fbase + 48] = v.w;
    part[l] = v.x * v.x + v.y * v.y + v.z * v.z + v.w * v.w;
  }
#pragma unroll
  for (int l = 0; l < 16; ++l) {
    float v = part[l];
    for (int off = 32; off > 0; off >>= 1) v += __shfl_down(v, off);
    if (lane == 0) red[l * 4 + wave] = v;
  }
  __syncthreads();
  if (tid < 16) {
    float s = red[tid * 4] + red[tid * 4 + 1] + red[tid * 4 + 2] + red[tid * 4 + 3];
    inv[tid] = 1.0f / fmaxf(sqrtf(s), 1e-12f);
  }
  __syncthreads();

  // write phase: lane -> (l-quarter q, f-row offset fi); wave w covers f in [w*256, w*256+256)
  const int q = lane & 3, fi = lane >> 2;
  const int lb = 4 * q;
  const size_t ob = (size_t)bb * FEAT * 126;
#pragma unroll
  for (int it = 0; it < 16; ++it) {
    int f = wave * 256 + it * 16 + fi;
    if (lb + 2 <= rem) {
      float* po = out + ob + (size_t)f * 126 + l0 + lb;
      float2 w0;
      w0.x = comb[(lb + 0) * CSTR + f] * inv[lb + 0];
      w0.y = comb[(lb + 1) * CSTR + f] * inv[lb + 1];
      *(float2*)po = w0;
      if (lb + 4 <= rem) {
        float2 w1;
        w1.x = comb[(lb + 2) * CSTR + f] * inv[lb + 2];
        w1.y = comb[(lb + 3) * CSTR + f] * inv[lb + 3];
        *(float2*)(po + 2) = w1;
      }
    }
  }
}

// ---------------- sentence head: l2norm(se @ Wp^T + bp) ----------------
__global__ __launch_bounds__(256) void sent_head(const float* __restrict__ se,
                                                 const float* __restrict__ Wp,
                                                 const float* __restrict__ bp,
                                                 float* __restrict__ out) {
  __shared__ float srow[768];
  __shared__ float ov[1024];
  __shared__ float red[4];
  const int b = blockIdx.x, tid = threadIdx.x;
  for (int i = tid; i < 768; i += 256) srow[i] = se[b * 768 + i];
  __syncthreads();
  float ss = 0.f;
#pragma unroll
  for (int it = 0; it < 4; ++it) {
    int f = tid + it * 256;
    const float4* w = (const float4*)(Wp + (size_t)f * 768);
    float acc = 0.f;
    for (int j = 0; j < 192; ++j) {
      float4 wv = w[j];
      float4 sv = *(const float4*)&srow[j * 4];
      acc += wv.x * sv.x + wv.y * sv.y + wv.z * sv.z + wv.w * sv.w;
    }
    acc += bp[f];
    ov[f] = acc;
    ss += acc * acc;
  }
  const int lane = tid & 63, wave = tid >> 6;
  for (int off = 32; off > 0; off >>= 1) ss += __shfl_down(ss, off);
  if (lane == 0) red[wave] = ss;
  __syncthreads();
  float tot = red[0] + red[1] + red[2] + red[3];
  float inv = 1.0f / fmaxf(sqrtf(tot), 1e-12f);
  for (int it = 0; it < 4; ++it) {
    int f = tid + it * 256;
    out[WORDS_OUT_ELEMS + (size_t)b * 1024 + f] = ov[f] * inv;
  }
}

extern "C" void kernel_launch(void* const* d_in, const int* in_sizes, int n_in,
                              void* d_out, int out_size, void* d_ws, size_t ws_size,
                              hipStream_t stream) {
  const float* words = (const float*)d_in[0];
  const float* sent = (const float*)d_in[1];
  const float* W2 = (const float*)d_in[2];
  const float* b2 = (const float*)d_in[3];
  const float* W3 = (const float*)d_in[4];
  const float* b3 = (const float*)d_in[5];
  const float* W4 = (const float*)d_in[6];
  const float* b4 = (const float*)d_in[7];
  const float* Wp = (const float*)d_in[8];
  const float* bp = (const float*)d_in[9];
  float* out = (float*)d_out;

  char* ws = (char*)d_ws;
  u16* A_bf = (u16*)(ws + 0);            // 12,582,912 elems -> 25,165,824 B
  u16* W2_bf = (u16*)(ws + 25165824);    // 1,572,864 -> 3,145,728 B
  u16* W3_bf = (u16*)(ws + 28311552);    // 2,359,296 -> 4,718,592 B
  u16* W4_bf = (u16*)(ws + 33030144);    // 3,145,728 -> 6,291,456 B
  u16* a_out = (u16*)(ws + 39321600);    // 16256*1024 bf16
  u16* b_out = (u16*)(ws + 72613888);    // 16128*1024 bf16
  u16* c_out = (u16*)(ws + 105644032);   // 16000*1024 bf16  (end 138,412,032 B)

  cvt_all<<<(N4_TOTAL + 255) / 256, 256, 0, stream>>>(words, W2, W3, W4,
                                                      A_bf, W2_bf, W3_bf, W4_bf);

  gemm_fused<<<dim3(8, 3, BSZ / 4), 512, 0, stream>>>(A_bf, W2_bf, W3_bf, W4_bf,
                                                      b2, b3, b4, a_out, b_out, c_out);

  combine_norm<<<dim3(8, BSZ), 256, 0, stream>>>(a_out, b_out, c_out, out);
  sent_head<<<BSZ, 256, 0, stream>>>(sent, Wp, bp, out);
}

// Round 7
// 499.904 us; speedup vs baseline: 1.4072x; 1.4072x over previous
//
#include <hip/hip_runtime.h>
#include <math.h>

typedef unsigned short u16;

#define BSZ 128
#define SEQL 128
#define DIM 768
#define FEAT 1024
#define WORDS_OUT_ELEMS (BSZ * FEAT * 126)  // 16,515,072

typedef __attribute__((ext_vector_type(8))) __bf16 bf16x8;
typedef __attribute__((ext_vector_type(4))) float f32x4;

__device__ __forceinline__ u16 f2bf(float x) {
  unsigned u = __float_as_uint(x);
  u += 0x7FFFu + ((u >> 16) & 1u);
  return (u16)(u >> 16);
}

__device__ __forceinline__ void gld_lds16(const void* g, void* l) {
  __builtin_amdgcn_global_load_lds(
      (const __attribute__((address_space(1))) void*)g,
      (__attribute__((address_space(3))) void*)l, 16, 0, 0);
}

#define WAITVM0 asm volatile("s_waitcnt vmcnt(0)" ::: "memory")
#define WAITVM6 asm volatile("s_waitcnt vmcnt(6)" ::: "memory")

// ---------------- fused fp32 -> bf16 convert ----------------
#define N4_WORDS 3145728
#define N4_W2 393216
#define N4_W3 589824
#define N4_W4 786432
#define N4_TOTAL (N4_WORDS + N4_W2 + N4_W3 + N4_W4)  // 4,915,200

__global__ __launch_bounds__(256) void cvt_all(const float* __restrict__ words,
                                               const float* __restrict__ W2,
                                               const float* __restrict__ W3,
                                               const float* __restrict__ W4,
                                               u16* __restrict__ dA, u16* __restrict__ d2,
                                               u16* __restrict__ d3, u16* __restrict__ d4) {
  int i = blockIdx.x * 256 + threadIdx.x;
  if (i >= N4_TOTAL) return;
  const float* src;
  u16* dst;
  int j = i;
  if (j < N4_WORDS) {
    src = words; dst = dA;
  } else if ((j -= N4_WORDS) < N4_W2) {
    src = W2; dst = d2;
  } else if ((j -= N4_W2) < N4_W3) {
    src = W3; dst = d3;
  } else {
    j -= N4_W3; src = W4; dst = d4;
  }
  float4 v = ((const float4*)src)[j];
  ushort4 o;
  o.x = f2bf(v.x); o.y = f2bf(v.y); o.z = f2bf(v.z); o.w = f2bf(v.w);
  ((ushort4*)dst)[j] = o;
}

// ---------------- conv GEMM ----------------
// R9: m201-faithful phase skeleton on R7's proven geometry/staging.
// R7 failure isolated: reads AFTER the phase barrier -> latency exposed per
// phase. m201 places reads BEFORE the barrier, lgkmcnt(0) AFTER -> the
// barrier wait doubles as the latency window (their 45.7->62% MfmaUtil).
// R8 failure: 2 waves/SIMD => 256 unified regs/wave; acc128 + dbl-frag sets
// can't fit -> spill. So: ONE frag set (af4+wf4), reads-before-barrier.
// Per k-step: 4 phases (kc x mi-half), each {reads; stage duty; s_barrier;
// lgkmcnt(0)+sched_barrier(0) [rule 18]; setprio(1); 16 MFMA; setprio(0);
// s_barrier}. X(d+1) staged in FIRST k-step of d0 (max flight), W(s+1)
// split P0/P1. Step-end vmcnt(6) when X in flight (W loads are oldest 2 of
// 10 -> land at 6), else vmcnt(0). All stage-issues follow the barrier that
// retired prior reads of the target buffer (WAR-safe); consumers read only
// after the vmcnt+barrier that published the staged data (RAW-safe).
__device__ __forceinline__ void stage_half(const u16* __restrict__ gbase, int stride,
                                           u16* __restrict__ ldsbase, int half,
                                           int wave, int lane) {
  int slot = half * 512 + wave * 64 + lane;
  int r = slot >> 3, c = slot & 7;
  const u16* src = gbase + (size_t)r * stride + ((c ^ (r & 7)) * 8);
  unsigned uofs = __builtin_amdgcn_readfirstlane((unsigned)((half * 512 + wave * 64) * 8));
  gld_lds16(src, ldsbase + uofs);
}

__device__ __forceinline__ void stage_tile512(const u16* __restrict__ gbase, int stride,
                                              u16* __restrict__ ldsbase, int wave, int lane) {
  stage_half(gbase, stride, ldsbase, 0, wave, lane);
  stage_half(gbase, stride, ldsbase, 1, wave, lane);
}

// stage both halves of X batch q for next d0
#define STX2(q)                                                                             \
  {                                                                                         \
    stage_half(xg + (size_t)(q) * 98304 + dd + 64, 768, Xnxt + (q) * 8192, 0, wave, lane);  \
    stage_half(xg + (size_t)(q) * 98304 + dd + 64, 768, Xnxt + (q) * 8192, 1, wave, lane);  \
  }

// one phase: reads BEFORE barrier, lgkm(0) after, 16 MFMA. DUTY = stage issues.
#define PHASE(kc, mh, DUTY)                                                          \
  {                                                                                  \
    _Pragma("unroll") for (int i = 0; i < 4; ++i) {                                  \
      int row = mh * 64 + i * 16 + frow + k;                                         \
      af[i] = *(const bf16x8*)&xb[(row * 8 + ((kc * 4 + fq) ^ (row & 7))) * 8];      \
    }                                                                                \
    if (mh == 0) {                                                                   \
      _Pragma("unroll") for (int ni = 0; ni < 4; ++ni) {                             \
        int row = wn + ni * 16 + frow;                                               \
        wf[ni] = *(const bf16x8*)&wcur[(row * 8 + ((kc * 4 + fq) ^ (row & 7))) * 8]; \
      }                                                                              \
    }                                                                                \
    DUTY;                                                                            \
    __builtin_amdgcn_s_barrier();                                                    \
    asm volatile("s_waitcnt lgkmcnt(0)" ::: "memory");                               \
    __builtin_amdgcn_sched_barrier(0);                                               \
    __builtin_amdgcn_s_setprio(1);                                                   \
    _Pragma("unroll") for (int i = 0; i < 4; ++i)                                    \
        _Pragma("unroll") for (int ni = 0; ni < 4; ++ni)                             \
            acc[mh * 4 + i][ni] = __builtin_amdgcn_mfma_f32_16x16x32_bf16(           \
                af[i], wf[ni], acc[mh * 4 + i][ni], 0, 0, 0);                        \
    __builtin_amdgcn_s_setprio(0);                                                   \
  }

template <int K>
__device__ __forceinline__ void run_branch(const u16* __restrict__ A,
                                           const u16* __restrict__ W,
                                           const float* __restrict__ bias,
                                           u16* __restrict__ C,
                                           int b0, int tile_n, u16* lds) {
  const int KD = K * 768;
  const int Lp = 129 - K;  // 127,126,125
  const int S = 12 * K;
  const int tid = threadIdx.x;
  const int wave = tid >> 6, lane = tid & 63;
  const int frow = lane & 15;
  const int fq = lane >> 4;
  const int wq = wave >> 1;        // batch of the quad (0..3)
  const int wn = (wave & 1) * 64;  // N-half

  const u16* xg = A + (size_t)b0 * 98304;  // batch q at +q*98304
  const u16* wg = W + (size_t)tile_n * 128 * KD;

  f32x4 acc[8][4];
#pragma unroll
  for (int mi = 0; mi < 8; ++mi)
#pragma unroll
    for (int ni = 0; ni < 4; ++ni) acc[mi][ni] = 0.0f;

  // prologue: X(d0=0) all 4 batches + W(s=0); full drain once
#pragma unroll
  for (int q = 0; q < 4; ++q)
    stage_tile512(xg + (size_t)q * 98304, 768, lds + q * 8192, wave, lane);
  stage_tile512(wg, KD, lds + 65536, wave, lane);
  WAITVM0;
  __builtin_amdgcn_sched_barrier(0);
  __syncthreads();

  for (int d0i = 0; d0i < 12; ++d0i) {
    const int dd = d0i * 64;
    u16* Xcur = (d0i & 1) ? (lds + 32768) : lds;
    u16* Xnxt = (d0i & 1) ? lds : (lds + 32768);
    const u16* xb = Xcur + wq * 8192;
#pragma unroll
    for (int k = 0; k < K; ++k) {
      const int s = d0i * K + k;
      const bool lastk = (k == K - 1);
      const bool stx = (k == 0) && (d0i < 11);  // stage X(d+1) in FIRST k-step
      const bool stw = (s + 1 < S);
      u16* wcur = (s & 1) ? (lds + 73728) : (lds + 65536);
      u16* wnxt = (s & 1) ? (lds + 65536) : (lds + 73728);
      const int nk = lastk ? 0 : k + 1;
      const int nd = lastk ? dd + 64 : dd;
      const u16* wsrc = wg + nk * 768 + nd;

      bf16x8 af[4], wf[4];
      PHASE(0, 0, {
        if (stw) stage_half(wsrc, KD, wnxt, 0, wave, lane);
        if (stx) STX2(0);
      })
      __builtin_amdgcn_s_barrier();
      PHASE(0, 1, {
        if (stw) stage_half(wsrc, KD, wnxt, 1, wave, lane);
        if (stx) STX2(1);
      })
      __builtin_amdgcn_s_barrier();
      PHASE(1, 0, {
        if (stx) STX2(2);
      })
      __builtin_amdgcn_s_barrier();
      PHASE(1, 1, {
        if (stx) STX2(3);
      })
      // step-end: publish W(s+1) (oldest 2 in flight); keep X(d+1) flying
      if (stx) { WAITVM6; } else { WAITVM0; }
      __builtin_amdgcn_sched_barrier(0);
      __builtin_amdgcn_s_barrier();
    }
  }

  float bv[4];
#pragma unroll
  for (int ni = 0; ni < 4; ++ni) bv[ni] = bias[tile_n * 128 + wn + ni * 16 + frow];
  const int bb = b0 + wq;
#pragma unroll
  for (int mi = 0; mi < 8; ++mi) {
#pragma unroll
    for (int r = 0; r < 4; ++r) {
      int mg = mi * 16 + fq * 4 + r;  // row within this wave's batch
      if (mg < Lp) {
        ushort4 hs;
        hs.x = f2bf(fmaxf(acc[mi][0][r] + bv[0], 0.0f));
        hs.y = f2bf(fmaxf(acc[mi][1][r] + bv[1], 0.0f));
        hs.z = f2bf(fmaxf(acc[mi][2][r] + bv[2], 0.0f));
        hs.w = f2bf(fmaxf(acc[mi][3][r] + bv[3], 0.0f));
        *(ushort4*)(C + (size_t)(bb * Lp + mg) * FEAT + tile_n * 128 + wn + frow * 4) = hs;
      }
    }
  }
}

__global__ __launch_bounds__(512, 1) void gemm_fused(const u16* __restrict__ A,
                                                     const u16* __restrict__ W2,
                                                     const u16* __restrict__ W3,
                                                     const u16* __restrict__ W4,
                                                     const float* __restrict__ b2,
                                                     const float* __restrict__ b3,
                                                     const float* __restrict__ b4,
                                                     u16* __restrict__ Ca,
                                                     u16* __restrict__ Cb,
                                                     u16* __restrict__ Cc) {
  __shared__ u16 lds[81920];  // 160 KB: X dbuf 2x64K + W dbuf 2x16K
  const int tile_n = blockIdx.x;
  const int z = blockIdx.y;
  const int b0 = blockIdx.z * 4;
  if (z == 0)
    run_branch<2>(A, W2, b2, Ca, b0, tile_n, lds);
  else if (z == 1)
    run_branch<3>(A, W3, b3, Cb, b0, tile_n, lds);
  else
    run_branch<4>(A, W4, b4, Cc, b0, tile_n, lds);
}

__device__ __forceinline__ float4 load_bf4(const u16* p) {
  uint2 q = *(const uint2*)p;
  float4 r;
  r.x = __uint_as_float((q.x & 0xFFFFu) << 16);
  r.y = __uint_as_float(q.x & 0xFFFF0000u);
  r.z = __uint_as_float((q.y & 0xFFFFu) << 16);
  r.w = __uint_as_float(q.y & 0xFFFF0000u);
  return r;
}

// ---------------- combine (max over branches) + L2 norm over FEAT + transposed write ----------------
// a: (BSZ,127,FEAT) b: (BSZ,126,FEAT) c: (BSZ,125,FEAT), bf16, PERMUTED col layout
// (stored index s within a 64-col chunk holds actual col (s&3)*16 + (s>>2)).
#define CSTR 1028

__global__ __launch_bounds__(256) void combine_norm(const u16* __restrict__ a,
                                                    const u16* __restrict__ b,
                                                    const u16* __restrict__ c,
                                                    float* __restrict__ out) {
  __shared__ float comb[16 * CSTR];  // 65.8 KB
  __shared__ float red[16 * 4];
  __shared__ float inv[16];
  const int tid = threadIdx.x;
  const int wave = tid >> 6, lane = tid & 63;
  const int l0 = blockIdx.x * 16;
  const int bb = blockIdx.y;
  const int rem = (126 - l0 < 16) ? (126 - l0) : 16;  // 16, last block 14
  const int f0 = tid * 4;                       // stored (permuted) index
  const int chunk = tid >> 4, frow = tid & 15;  // de-permute params
  const int fbase = chunk * 64 + frow;          // actual col for ni=0 (then +16 per ni)

  float part[16];
#pragma unroll
  for (int l = 0; l < 16; ++l) {
    int lg = l0 + l;
    float4 v = make_float4(0.f, 0.f, 0.f, 0.f);
    if (lg < 126) {
      v = load_bf4(a + (size_t)(bb * 127 + lg) * 1024 + f0);
      if (lg < 125) {
        float4 vb = load_bf4(b + (size_t)(bb * 126 + lg) * 1024 + f0);
        v.x = fmaxf(v.x, vb.x); v.y = fmaxf(v.y, vb.y);
        v.z = fmaxf(v.z, vb.z); v.w = fmaxf(v.w, vb.w);
      }
      if (lg < 124) {
        float4 vc = load_bf4(c + (size_t)(bb * 125 + lg) * 1024 + f0);
        v.x = fmaxf(v.x, vc.x); v.y = fmaxf(v.y, vc.y);
        v.z = fmaxf(v.z, vc.z); v.w = fmaxf(v.w, vc.w);
      }
    }
    comb[l * CSTR + fbase + 0] = v.x;
    comb[l * CSTR + fbase + 16] = v.y;
    comb[l * CSTR + fbase + 32] = v.z;
    comb[l * CSTR + fbase + 48] = v.w;
    part[l] = v.x * v.x + v.y * v.y + v.z * v.z + v.w * v.w;
  }
#pragma unroll
  for (int l = 0; l < 16; ++l) {
    float v = part[l];
    for (int off = 32; off > 0; off >>= 1) v += __shfl_down(v, off);
    if (lane == 0) red[l * 4 + wave] = v;
  }
  __syncthreads();
  if (tid < 16) {
    float s = red[tid * 4] + red[tid * 4 + 1] + red[tid * 4 + 2] + red[tid * 4 + 3];
    inv[tid] = 1.0f / fmaxf(sqrtf(s), 1e-12f);
  }
  __syncthreads();

  // write phase: lane -> (l-quarter q, f-row offset fi); wave w covers f in [w*256, w*256+256)
  const int q = lane & 3, fi = lane >> 2;
  const int lb = 4 * q;
  const size_t ob = (size_t)bb * FEAT * 126;
#pragma unroll
  for (int it = 0; it < 16; ++it) {
    int f = wave * 256 + it * 16 + fi;
    if (lb + 2 <= rem) {
      float* po = out + ob + (size_t)f * 126 + l0 + lb;
      float2 w0;
      w0.x = comb[(lb + 0) * CSTR + f] * inv[lb + 0];
      w0.y = comb[(lb + 1) * CSTR + f] * inv[lb + 1];
      *(float2*)po = w0;
      if (lb + 4 <= rem) {
        float2 w1;
        w1.x = comb[(lb + 2) * CSTR + f] * inv[lb + 2];
        w1.y = comb[(lb + 3) * CSTR + f] * inv[lb + 3];
        *(float2*)(po + 2) = w1;
      }
    }
  }
}

// ---------------- sentence head: l2norm(se @ Wp^T + bp) ----------------
__global__ __launch_bounds__(256) void sent_head(const float* __restrict__ se,
                                                 const float* __restrict__ Wp,
                                                 const float* __restrict__ bp,
                                                 float* __restrict__ out) {
  __shared__ float srow[768];
  __shared__ float ov[1024];
  __shared__ float red[4];
  const int b = blockIdx.x, tid = threadIdx.x;
  for (int i = tid; i < 768; i += 256) srow[i] = se[b * 768 + i];
  __syncthreads();
  float ss = 0.f;
#pragma unroll
  for (int it = 0; it < 4; ++it) {
    int f = tid + it * 256;
    const float4* w = (const float4*)(Wp + (size_t)f * 768);
    float acc = 0.f;
    for (int j = 0; j < 192; ++j) {
      float4 wv = w[j];
      float4 sv = *(const float4*)&srow[j * 4];
      acc += wv.x * sv.x + wv.y * sv.y + wv.z * sv.z + wv.w * sv.w;
    }
    acc += bp[f];
    ov[f] = acc;
    ss += acc * acc;
  }
  const int lane = tid & 63, wave = tid >> 6;
  for (int off = 32; off > 0; off >>= 1) ss += __shfl_down(ss, off);
  if (lane == 0) red[wave] = ss;
  __syncthreads();
  float tot = red[0] + red[1] + red[2] + red[3];
  float inv = 1.0f / fmaxf(sqrtf(tot), 1e-12f);
  for (int it = 0; it < 4; ++it) {
    int f = tid + it * 256;
    out[WORDS_OUT_ELEMS + (size_t)b * 1024 + f] = ov[f] * inv;
  }
}

extern "C" void kernel_launch(void* const* d_in, const int* in_sizes, int n_in,
                              void* d_out, int out_size, void* d_ws, size_t ws_size,
                              hipStream_t stream) {
  const float* words = (const float*)d_in[0];
  const float* sent = (const float*)d_in[1];
  const float* W2 = (const float*)d_in[2];
  const float* b2 = (const float*)d_in[3];
  const float* W3 = (const float*)d_in[4];
  const float* b3 = (const float*)d_in[5];
  const float* W4 = (const float*)d_in[6];
  const float* b4 = (const float*)d_in[7];
  const float* Wp = (const float*)d_in[8];
  const float* bp = (const float*)d_in[9];
  float* out = (float*)d_out;

  char* ws = (char*)d_ws;
  u16* A_bf = (u16*)(ws + 0);            // 12,582,912 elems -> 25,165,824 B
  u16* W2_bf = (u16*)(ws + 25165824);    // 1,572,864 -> 3,145,728 B
  u16* W3_bf = (u16*)(ws + 28311552);    // 2,359,296 -> 4,718,592 B
  u16* W4_bf = (u16*)(ws + 33030144);    // 3,145,728 -> 6,291,456 B
  u16* a_out = (u16*)(ws + 39321600);    // 16256*1024 bf16
  u16* b_out = (u16*)(ws + 72613888);    // 16128*1024 bf16
  u16* c_out = (u16*)(ws + 105644032);   // 16000*1024 bf16  (end 138,412,032 B)

  cvt_all<<<(N4_TOTAL + 255) / 256, 256, 0, stream>>>(words, W2, W3, W4,
                                                      A_bf, W2_bf, W3_bf, W4_bf);

  gemm_fused<<<dim3(8, 3, BSZ / 4), 512, 0, stream>>>(A_bf, W2_bf, W3_bf, W4_bf,
                                                      b2, b3, b4, a_out, b_out, c_out);

  combine_norm<<<dim3(8, BSZ), 256, 0, stream>>>(a_out, b_out, c_out, out);
  sent_head<<<BSZ, 256, 0, stream>>>(sent, Wp, bp, out);
}

// Round 8
// 490.276 us; speedup vs baseline: 1.4348x; 1.0196x over previous
//
#include <hip/hip_runtime.h>
#include <math.h>

typedef unsigned short u16;

#define BSZ 128
#define SEQL 128
#define DIM 768
#define FEAT 1024
#define WORDS_OUT_ELEMS (BSZ * FEAT * 126)  // 16,515,072

typedef __attribute__((ext_vector_type(8))) __bf16 bf16x8;
typedef __attribute__((ext_vector_type(4))) float f32x4;

__device__ __forceinline__ u16 f2bf(float x) {
  unsigned u = __float_as_uint(x);
  u += 0x7FFFu + ((u >> 16) & 1u);
  return (u16)(u >> 16);
}

__device__ __forceinline__ void gld_lds16(const void* g, void* l) {
  __builtin_amdgcn_global_load_lds(
      (const __attribute__((address_space(1))) void*)g,
      (__attribute__((address_space(3))) void*)l, 16, 0, 0);
}

// ---------------- fused fp32 -> bf16 convert ----------------
#define N4_WORDS 3145728
#define N4_W2 393216
#define N4_W3 589824
#define N4_W4 786432
#define N4_TOTAL (N4_WORDS + N4_W2 + N4_W3 + N4_W4)  // 4,915,200

__global__ __launch_bounds__(256) void cvt_all(const float* __restrict__ words,
                                               const float* __restrict__ W2,
                                               const float* __restrict__ W3,
                                               const float* __restrict__ W4,
                                               u16* __restrict__ dA, u16* __restrict__ d2,
                                               u16* __restrict__ d3, u16* __restrict__ d4) {
  int i = blockIdx.x * 256 + threadIdx.x;
  if (i >= N4_TOTAL) return;
  const float* src;
  u16* dst;
  int j = i;
  if (j < N4_WORDS) {
    src = words; dst = dA;
  } else if ((j -= N4_WORDS) < N4_W2) {
    src = W2; dst = d2;
  } else if ((j -= N4_W2) < N4_W3) {
    src = W3; dst = d3;
  } else {
    j -= N4_W3; src = W4; dst = d4;
  }
  float4 v = ((const float4*)src)[j];
  ushort4 o;
  o.x = f2bf(v.x); o.y = f2bf(v.y); o.z = f2bf(v.z); o.w = f2bf(v.w);
  ((ushort4*)dst)[j] = o;
}

// ---------------- conv GEMM (R5 structure, BANKED) ----------------
// Schedule search post-mortem (R7/R8/R9): every phase/barrier restructure
// lost to this simple 2-barrier loop (212us, MfmaUtil 49%, 0 conflicts,
// no spill). At 0.375 b128/MFMA, per-CU LDS time ~102us ~= MFMA ~110us;
// none of the m201-style schedules decoupled them on this problem (their
// headroom was bank-conflict elimination -- we already have 0). Banking R5.
// Geometry: 256 thr, 4 waves as 2(batch)x2(N), wave 128x64 out via 8x4
// frags (acc 128 VGPR, no spill), block = batch-pair x 128 feat.
__device__ __forceinline__ void stage_tile(const u16* __restrict__ gbase, int stride,
                                           u16* __restrict__ ldsbase, int wave, int lane) {
#pragma unroll
  for (int i = 0; i < 4; ++i) {
    int slot = i * 256 + wave * 64 + lane;
    int r = slot >> 3, c = slot & 7;
    const u16* src = gbase + (size_t)r * stride + ((c ^ (r & 7)) * 8);
    unsigned uofs = __builtin_amdgcn_readfirstlane((unsigned)((i * 256 + wave * 64) * 8));
    gld_lds16(src, ldsbase + uofs);
  }
}

template <int K>
__device__ __forceinline__ void run_branch(const u16* __restrict__ A,
                                           const u16* __restrict__ W,
                                           const float* __restrict__ bias,
                                           u16* __restrict__ C,
                                           int b0, int tile_n, u16* lds) {
  const int KD = K * 768;
  const int Lp = 129 - K;  // 127,126,125
  const int tid = threadIdx.x;
  const int wave = tid >> 6, lane = tid & 63;
  u16* Xs = lds;               // 256 rows x 64 cols = 32 KB (16384 u16)
  u16* Wb0 = lds + 16384;      // W double buffer, 16 KB each
  u16* Wb1 = lds + 24576;

  const int bsel = wave & 1;        // which batch of the pair (M half)
  const int wm = bsel * 128;        // absolute LDS row base for this wave
  const int wn = (wave >> 1) * 64;
  const int frow = lane & 15;
  const int fq = lane >> 4;

  const u16* xg0 = A + (size_t)b0 * 98304;
  const u16* xg1 = A + (size_t)(b0 + 1) * 98304;
  const u16* wg = W + (size_t)tile_n * 128 * KD;

  f32x4 acc[8][4];
#pragma unroll
  for (int mi = 0; mi < 8; ++mi)
#pragma unroll
    for (int ni = 0; ni < 4; ++ni) acc[mi][ni] = 0.0f;

  for (int d0 = 0; d0 < 768; d0 += 64) {
    stage_tile(xg0 + d0, 768, Xs, wave, lane);
    stage_tile(xg1 + d0, 768, Xs + 8192, wave, lane);
    stage_tile(wg + d0, KD, Wb0, wave, lane);  // k = 0 slice
    __syncthreads();
#pragma unroll
    for (int k = 0; k < K; ++k) {
      if (k + 1 < K)  // prefetch next W slice into the other buffer
        stage_tile(wg + (k + 1) * 768 + d0, KD, ((k + 1) & 1) ? Wb1 : Wb0, wave, lane);
      const u16* wbuf = (k & 1) ? Wb1 : Wb0;
#pragma unroll
      for (int kc = 0; kc < 2; ++kc) {
        bf16x8 af[8], wf[4];
#pragma unroll
        for (int mi = 0; mi < 8; ++mi) {
          int row = wm + mi * 16 + frow + k;  // k-shifted raw-row read
          af[mi] = *(const bf16x8*)&Xs[(row * 8 + ((kc * 4 + fq) ^ (row & 7))) * 8];
        }
#pragma unroll
        for (int ni = 0; ni < 4; ++ni) {
          int row = wn + ni * 16 + frow;
          wf[ni] = *(const bf16x8*)&wbuf[(row * 8 + ((kc * 4 + fq) ^ (row & 7))) * 8];
        }
#pragma unroll
        for (int mi = 0; mi < 8; ++mi)
#pragma unroll
          for (int ni = 0; ni < 4; ++ni)
            acc[mi][ni] = __builtin_amdgcn_mfma_f32_16x16x32_bf16(af[mi], wf[ni],
                                                                  acc[mi][ni], 0, 0, 0);
      }
      __syncthreads();
    }
  }

  float bv[4];
#pragma unroll
  for (int ni = 0; ni < 4; ++ni) bv[ni] = bias[tile_n * 128 + wn + ni * 16 + frow];
  const int bb = b0 + bsel;
#pragma unroll
  for (int mi = 0; mi < 8; ++mi) {
#pragma unroll
    for (int r = 0; r < 4; ++r) {
      int mg = mi * 16 + fq * 4 + r;  // row within this wave's batch
      if (mg < Lp) {
        ushort4 hs;
        hs.x = f2bf(fmaxf(acc[mi][0][r] + bv[0], 0.0f));
        hs.y = f2bf(fmaxf(acc[mi][1][r] + bv[1], 0.0f));
        hs.z = f2bf(fmaxf(acc[mi][2][r] + bv[2], 0.0f));
        hs.w = f2bf(fmaxf(acc[mi][3][r] + bv[3], 0.0f));
        *(ushort4*)(C + (size_t)(bb * Lp + mg) * FEAT + tile_n * 128 + wn + frow * 4) = hs;
      }
    }
  }
}

__global__ __launch_bounds__(256, 2) void gemm_fused(const u16* __restrict__ A,
                                                     const u16* __restrict__ W2,
                                                     const u16* __restrict__ W3,
                                                     const u16* __restrict__ W4,
                                                     const float* __restrict__ b2,
                                                     const float* __restrict__ b3,
                                                     const float* __restrict__ b4,
                                                     u16* __restrict__ Ca,
                                                     u16* __restrict__ Cb,
                                                     u16* __restrict__ Cc) {
  __shared__ u16 lds[32768];  // 64 KB: Xs(32K) + 2 x W(16K)
  const int tile_n = blockIdx.x;
  const int z = blockIdx.y;
  const int b0 = blockIdx.z * 2;
  if (z == 0)
    run_branch<2>(A, W2, b2, Ca, b0, tile_n, lds);
  else if (z == 1)
    run_branch<3>(A, W3, b3, Cb, b0, tile_n, lds);
  else
    run_branch<4>(A, W4, b4, Cc, b0, tile_n, lds);
}

__device__ __forceinline__ float4 load_bf4(const u16* p) {
  uint2 q = *(const uint2*)p;
  float4 r;
  r.x = __uint_as_float((q.x & 0xFFFFu) << 16);
  r.y = __uint_as_float(q.x & 0xFFFF0000u);
  r.z = __uint_as_float((q.y & 0xFFFFu) << 16);
  r.w = __uint_as_float(q.y & 0xFFFF0000u);
  return r;
}

// ---------------- combine (max over branches) + L2 norm over FEAT + transposed write ----------------
// a: (BSZ,127,FEAT) b: (BSZ,126,FEAT) c: (BSZ,125,FEAT), bf16, PERMUTED col layout
// (stored index s within a 64-col chunk holds actual col (s&3)*16 + (s>>2)).
#define CSTR 1028

__global__ __launch_bounds__(256) void combine_norm(const u16* __restrict__ a,
                                                    const u16* __restrict__ b,
                                                    const u16* __restrict__ c,
                                                    float* __restrict__ out) {
  __shared__ float comb[16 * CSTR];  // 65.8 KB
  __shared__ float red[16 * 4];
  __shared__ float inv[16];
  const int tid = threadIdx.x;
  const int wave = tid >> 6, lane = tid & 63;
  const int l0 = blockIdx.x * 16;
  const int bb = blockIdx.y;
  const int rem = (126 - l0 < 16) ? (126 - l0) : 16;  // 16, last block 14
  const int f0 = tid * 4;                       // stored (permuted) index
  const int chunk = tid >> 4, frow = tid & 15;  // de-permute params
  const int fbase = chunk * 64 + frow;          // actual col for ni=0 (then +16 per ni)

  float part[16];
#pragma unroll
  for (int l = 0; l < 16; ++l) {
    int lg = l0 + l;
    float4 v = make_float4(0.f, 0.f, 0.f, 0.f);
    if (lg < 126) {
      v = load_bf4(a + (size_t)(bb * 127 + lg) * 1024 + f0);
      if (lg < 125) {
        float4 vb = load_bf4(b + (size_t)(bb * 126 + lg) * 1024 + f0);
        v.x = fmaxf(v.x, vb.x); v.y = fmaxf(v.y, vb.y);
        v.z = fmaxf(v.z, vb.z); v.w = fmaxf(v.w, vb.w);
      }
      if (lg < 124) {
        float4 vc = load_bf4(c + (size_t)(bb * 125 + lg) * 1024 + f0);
        v.x = fmaxf(v.x, vc.x); v.y = fmaxf(v.y, vc.y);
        v.z = fmaxf(v.z, vc.z); v.w = fmaxf(v.w, vc.w);
      }
    }
    comb[l * CSTR + fbase + 0] = v.x;
    comb[l * CSTR + fbase + 16] = v.y;
    comb[l * CSTR + fbase + 32] = v.z;
    comb[l * CSTR + fbase + 48] = v.w;
    part[l] = v.x * v.x + v.y * v.y + v.z * v.z + v.w * v.w;
  }
#pragma unroll
  for (int l = 0; l < 16; ++l) {
    float v = part[l];
    for (int off = 32; off > 0; off >>= 1) v += __shfl_down(v, off);
    if (lane == 0) red[l * 4 + wave] = v;
  }
  __syncthreads();
  if (tid < 16) {
    float s = red[tid * 4] + red[tid * 4 + 1] + red[tid * 4 + 2] + red[tid * 4 + 3];
    inv[tid] = 1.0f / fmaxf(sqrtf(s), 1e-12f);
  }
  __syncthreads();

  // write phase: lane -> (l-quarter q, f-row offset fi); wave w covers f in [w*256, w*256+256)
  const int q = lane & 3, fi = lane >> 2;
  const int lb = 4 * q;
  const size_t ob = (size_t)bb * FEAT * 126;
#pragma unroll
  for (int it = 0; it < 16; ++it) {
    int f = wave * 256 + it * 16 + fi;
    if (lb + 2 <= rem) {
      float* po = out + ob + (size_t)f * 126 + l0 + lb;
      float2 w0;
      w0.x = comb[(lb + 0) * CSTR + f] * inv[lb + 0];
      w0.y = comb[(lb + 1) * CSTR + f] * inv[lb + 1];
      *(float2*)po = w0;
      if (lb + 4 <= rem) {
        float2 w1;
        w1.x = comb[(lb + 2) * CSTR + f] * inv[lb + 2];
        w1.y = comb[(lb + 3) * CSTR + f] * inv[lb + 3];
        *(float2*)(po + 2) = w1;
      }
    }
  }
}

// ---------------- sentence head: l2norm(se @ Wp^T + bp) ----------------
// R10: 1024 threads (16 waves = 4/SIMD) instead of 256 (4 waves = 1/SIMD).
// Old version: half the GPU idle AND only 1 wave/SIMD to hide the L2 load
// latency of the 3.1 MB Wp stream -> suspected latency-bound sink in the
// ~265us non-gemm budget. One f per thread, same fp32 math (zero precision
// risk), single 16-wave in-block reduction.
__global__ __launch_bounds__(1024) void sent_head(const float* __restrict__ se,
                                                  const float* __restrict__ Wp,
                                                  const float* __restrict__ bp,
                                                  float* __restrict__ out) {
  __shared__ float srow[768];
  __shared__ float red[16];
  const int b = blockIdx.x, tid = threadIdx.x;
  if (tid < 768) srow[tid] = se[b * 768 + tid];
  __syncthreads();
  const float4* w = (const float4*)(Wp + (size_t)tid * 768);
  float acc = 0.f;
#pragma unroll 4
  for (int j = 0; j < 192; ++j) {
    float4 wv = w[j];
    float4 sv = *(const float4*)&srow[j * 4];
    acc += wv.x * sv.x + wv.y * sv.y + wv.z * sv.z + wv.w * sv.w;
  }
  acc += bp[tid];
  const int lane = tid & 63, wave = tid >> 6;
  float ss = acc * acc;
  for (int off = 32; off > 0; off >>= 1) ss += __shfl_down(ss, off);
  if (lane == 0) red[wave] = ss;
  __syncthreads();
  if (tid == 0) {
    float t = 0.f;
#pragma unroll
    for (int i = 0; i < 16; ++i) t += red[i];
    red[0] = 1.0f / fmaxf(sqrtf(t), 1e-12f);
  }
  __syncthreads();
  out[WORDS_OUT_ELEMS + (size_t)b * 1024 + tid] = acc * red[0];
}

extern "C" void kernel_launch(void* const* d_in, const int* in_sizes, int n_in,
                              void* d_out, int out_size, void* d_ws, size_t ws_size,
                              hipStream_t stream) {
  const float* words = (const float*)d_in[0];
  const float* sent = (const float*)d_in[1];
  const float* W2 = (const float*)d_in[2];
  const float* b2 = (const float*)d_in[3];
  const float* W3 = (const float*)d_in[4];
  const float* b3 = (const float*)d_in[5];
  const float* W4 = (const float*)d_in[6];
  const float* b4 = (const float*)d_in[7];
  const float* Wp = (const float*)d_in[8];
  const float* bp = (const float*)d_in[9];
  float* out = (float*)d_out;

  char* ws = (char*)d_ws;
  u16* A_bf = (u16*)(ws + 0);            // 12,582,912 elems -> 25,165,824 B
  u16* W2_bf = (u16*)(ws + 25165824);    // 1,572,864 -> 3,145,728 B
  u16* W3_bf = (u16*)(ws + 28311552);    // 2,359,296 -> 4,718,592 B
  u16* W4_bf = (u16*)(ws + 33030144);    // 3,145,728 -> 6,291,456 B
  u16* a_out = (u16*)(ws + 39321600);    // 16256*1024 bf16
  u16* b_out = (u16*)(ws + 72613888);    // 16128*1024 bf16
  u16* c_out = (u16*)(ws + 105644032);   // 16000*1024 bf16  (end 138,412,032 B)

  cvt_all<<<(N4_TOTAL + 255) / 256, 256, 0, stream>>>(words, W2, W3, W4,
                                                      A_bf, W2_bf, W3_bf, W4_bf);

  gemm_fused<<<dim3(8, 3, BSZ / 2), 256, 0, stream>>>(A_bf, W2_bf, W3_bf, W4_bf,
                                                      b2, b3, b4, a_out, b_out, c_out);

  combine_norm<<<dim3(8, BSZ), 256, 0, stream>>>(a_out, b_out, c_out, out);
  sent_head<<<BSZ, 1024, 0, stream>>>(sent, Wp, bp, out);
}